// Round 6
// baseline (839.877 us; speedup 1.0000x reference)
//
#include <hip/hip_runtime.h>

// SimpleEncoder R11: LSTM(B=4096,S=512,I=3,H=16) + Linear(16->5) + clip(+-10)
//
// R11 = R10 with ONE change: amdgpu_waves_per_eu(2, 2) instead of (2).
//
// R10's 797us regression was REGISTER SPILL, not the algorithm: VGPR_Count=64
// vs a ~80-110 persistent working set (wp[16] f32x2=32 + xwp 6 + wl 8 +
// staging 20 + misc). waves_per_eu(2) has no max -> allocator targeted 8
// waves/EU -> 64-VGPR cap -> weights spilled to scratch, reloaded per step
// (VALUBusy 19%, WRITE_SIZE 40.96->49.9MB spill write-through). Same bug
// retroactively confounds R8 (also VGPR=64): the "2-wave family is
// break-even" conclusion came from a spilled build. Pinning min=max=2 gives
// the allocator 512/2=256 VGPRs/wave; grid still provides 2 waves/SIMD
// (512 blocks x 4 waves; 32KB LDS -> 2+ blocks/CU co-resident).
//
// Structure (unchanged from R10) -- GATE-split, 32 lanes/batch:
// lane (u = l&15, hh = (l>>4)&1) computes gates (i,f) [hh=0] or (g,o)
// [hh=1] for unit u -- 2 full-length dots/lane.
//  - MAC issue conserved per batch (19 pk_fma/lane).
//  - gate trans conserved: halves compute DIFFERENT gates in the SAME
//    instructions; sigmoid/tanh signs folded into per-lane weight scales
//    {L,L,-2L,L} so all lanes run E=exp2(-z), paired rcp.
//  - gate exchange: 2 ds_swizzle xor-16; cell update redundant in both
//    halves (bit-identical copies -> h coherent).
//  - head k-split by hh: 8 fma + swizzle-reduce; hh=0,u<5 stores.
//  - per-wave-only duplication: 16-DPP bcast + cell trans + loop (~70cyc).
// Keeps R9's scaled-cs recurrence + quad accumulation chains.

#define TS 512
#define LOG2E 1.44269504088896340736f

typedef float f32x2 __attribute__((ext_vector_type(2)));

// DPP row_newbcast:K -- broadcast lane K of each 16-lane row to the row.
#define BCAST(K) hbr[K] = __int_as_float( \
    __builtin_amdgcn_update_dpp(0, hvi, 0x150 + (K), 0xf, 0xf, true))
#define BCAST_ALL() \
  BCAST(0); BCAST(1); BCAST(2); BCAST(3); BCAST(4); BCAST(5); BCAST(6); BCAST(7); \
  BCAST(8); BCAST(9); BCAST(10); BCAST(11); BCAST(12); BCAST(13); BCAST(14); BCAST(15)

// xor-16 lane swap within each 32-lane group (ds_swizzle BitMode 0x401F)
static __device__ __forceinline__ float swz16(float v) {
  return __int_as_float(__builtin_amdgcn_ds_swizzle(__float_as_int(v), 0x401F));
}

__global__ __launch_bounds__(256)
__attribute__((amdgpu_waves_per_eu(2, 2)))
void lstm_enc_kernel(const float* __restrict__ x,
                     const float* __restrict__ W_ih,
                     const float* __restrict__ W_hh,
                     const float* __restrict__ b_ih,
                     const float* __restrict__ b_hh,
                     const float* __restrict__ W_lin,
                     const float* __restrict__ b_lin,
                     float* __restrict__ out) {
  const int tid = threadIdx.x;
  const int u   = tid & 15;          // hidden unit
  const int hh  = (tid >> 4) & 1;    // gate-half: 0 -> (i,f), 1 -> (g,o)
  const int g8  = tid >> 5;          // batch slot within block (0..7)
  const int batch = blockIdx.x * 8 + g8;
  const int jo = (u < 5) ? u : 0;    // clamped row for W_lin loads

  // x staging: xs[parity][step-in-chunk(128)][batch-slot] as float4 (pad 4th)
  __shared__ float4 xs[2][128][8];
  float4* xsf = &xs[0][0][0];        // flat: idx = (s & 255)*8 + g8

  // ---- per-lane weights: this lane's GATE PAIR, full k, signs+log2e folded.
  // hh=0: rows (u, u+16) scales (L, L)      -> z = (L i, L f),  E=exp2(-z)
  // hh=1: rows (u+32, u+48) scales (-2L, L) -> z = (-2L g, L o), E=exp2(-z)
  //   sg = rcp(1+exp2(2L g)) = 1/(1+e^{2g}); og = sigmoid(o)  [paired rcp]
  const int r0 = u + (hh ? 32 : 0);
  const int r1 = u + (hh ? 48 : 16);
  const float s0 = hh ? (-2.0f * LOG2E) : LOG2E;
  const float s1 = LOG2E;

  f32x2 wp[16];                      // {W[r0][k]*s0, W[r1][k]*s1}
  float wl[8];                       // head, k-half 8hh..8hh+7
#pragma unroll
  for (int k = 0; k < 16; ++k) {
    wp[k] = f32x2{W_hh[r0 * 16 + k] * s0, W_hh[r1 * 16 + k] * s1};
  }
#pragma unroll
  for (int e = 0; e < 8; ++e) wl[e] = W_lin[jo * 16 + hh * 8 + e];
  f32x2 xwp[3];
#pragma unroll
  for (int i = 0; i < 3; ++i) {
    xwp[i] = f32x2{W_ih[r0 * 3 + i] * s0, W_ih[r1 * 3 + i] * s1};
  }
  const f32x2 bp = f32x2{(b_ih[r0] + b_hh[r0]) * s0,
                         (b_ih[r1] + b_hh[r1]) * s1};
  const float bl = hh ? 0.f : b_lin[jo];

  const float* __restrict__ xb = x + (size_t)batch * (TS * 3);
  float* __restrict__ ob = out + (size_t)batch * (TS * 5) + u;
  const bool storer = (u < 5) && (hh == 0);

  // ---- staging (R8's scheme): 128-step chunks (384 floats/batch);
  // lane l32 = tid&31 owns steps 4*l32..4*l32+3 of batch slot g8. Intra-wave
  // (wave holds slots 2w,2w+1 and stages exactly those) -> no barriers.
  const int l32 = tid & 31;
  const float* xc0 = xb + l32 * 12;  // xb already includes this lane's batch
  float4 q0, q1, q2;
  q0 = *(const float4*)(xc0 + 0);
  q1 = *(const float4*)(xc0 + 4);
  q2 = *(const float4*)(xc0 + 8);
  {
    const int wb = (l32 * 4) * 8 + g8;     // parity 0 base
    xsf[wb +  0] = float4{q0.x, q0.y, q0.z, 0.f};
    xsf[wb +  8] = float4{q0.w, q1.x, q1.y, 0.f};
    xsf[wb + 16] = float4{q1.z, q1.w, q2.x, 0.f};
    xsf[wb + 24] = float4{q2.y, q2.z, q2.w, 0.f};
  }
  q0 = *(const float4*)(xc0 + 384 + 0);
  q1 = *(const float4*)(xc0 + 384 + 4);
  q2 = *(const float4*)(xc0 + 384 + 8);

  // prefetch x for steps 0 and 1
  float4 xr[2];
  xr[0] = xsf[0 * 8 + g8];
  xr[1] = xsf[1 * 8 + g8];

  float h = 0.0f, cs = 0.0f;         // cs = 2*LOG2E * c (scaled cell)

  auto step = [&](int s, int slot) {
    const float4 xt = xr[slot];
    // issue ds_read for step s+2 into the slot just freed
    xr[slot] = xsf[(((s + 2) & 255) << 3) + g8];

    // broadcast h_{t-1} across each 16-lane row (every row holds identical
    // per-unit h for its (batch, half) -> hbr[k] = h[k] of OUR batch)
    float hbr[16];
    const int hvi = __float_as_int(h);
    BCAST_ALL();

    // this lane's gate-pair pre-activations: quad pk_fma chains (depth ~5)
    f32x2 aa = bp, ab = f32x2{0.f, 0.f}, ac = f32x2{0.f, 0.f}, ad = f32x2{0.f, 0.f};
    float oa0 = bl, oa1 = 0.f;
    aa = f32x2{xt.x, xt.x} * xwp[0] + aa;
    ab = f32x2{xt.y, xt.y} * xwp[1] + ab;
    ac = f32x2{xt.z, xt.z} * xwp[2] + ac;
#pragma unroll
    for (int k = 0; k < 16; k += 4) {
      const f32x2 h0 = f32x2{hbr[k],     hbr[k]};
      const f32x2 h1 = f32x2{hbr[k + 1], hbr[k + 1]};
      const f32x2 h2 = f32x2{hbr[k + 2], hbr[k + 2]};
      const f32x2 h3 = f32x2{hbr[k + 3], hbr[k + 3]};
      aa = h0 * wp[k]     + aa;
      ab = h1 * wp[k + 1] + ab;
      ac = h2 * wp[k + 2] + ac;
      ad = h3 * wp[k + 3] + ad;
    }
    // head partial over this lane's k-half (hbr is full-k on every lane)
#pragma unroll
    for (int e = 0; e < 8; e += 2) {
      oa0 = fmaf(hbr[hh * 8 + e],     wl[e],     oa0);
      oa1 = fmaf(hbr[hh * 8 + e + 1], wl[e + 1], oa1);
    }
    const f32x2 z = (aa + ab) + (ac + ad);

    // head: cross-half reduce + store out[s-1]
    const float oal = oa0 + oa1;
    const float oa = oal + swz16(oal);
    if (s > 0 && storer) {
      ob[(s - 1) * 5] = fminf(fmaxf(oa, -10.0f), 10.0f);
    }

    // uniform paired-rcp acts: hh=0 -> (v0,v1)=(ig,fg); hh=1 -> (sg,og)
    const float E0 = __builtin_amdgcn_exp2f(-z.x);
    const float E1 = __builtin_amdgcn_exp2f(-z.y);
    const float d0 = 1.0f + E0, d1 = 1.0f + E1;
    const float R  = __builtin_amdgcn_rcpf(d0 * d1);
    const float v0 = d1 * R;
    const float v1 = d0 * R;

    // exchange with the other half (bitwise copies -> both halves coherent)
    const float w0 = swz16(v0);
    const float w1 = swz16(v1);
    const float ig = hh ? w0 : v0;
    const float fg = hh ? w1 : v1;
    const float sg = hh ? v0 : w0;
    const float og = hh ? v1 : w1;

    // scaled cell: cs = 2L*c; gg2 = 2L*tanh(g) = 2L - 4L*sg
    const float gg2 = fmaf(-4.0f * LOG2E, sg, 2.0f * LOG2E);
    cs = fmaf(fg, cs, ig * gg2);
    const float tc = fmaf(-2.0f,
        __builtin_amdgcn_rcpf(1.0f + __builtin_amdgcn_exp2f(cs)), 1.0f);
    h = og * tc;
  };

  for (int ch = 0; ch < 4; ++ch) {
    const int base = ch * 128;

    // first half of the chunk
#pragma unroll 2
    for (int v = 0; v < 64; ++v) step(base + v, v & 1);

    // mid-chunk: stage chunk ch+1 (regs loaded ~128 steps ago), start ch+2 loads
    if (ch < 3) {
      const int p = (ch + 1) & 1;
      const int wb = (p * 128 + l32 * 4) * 8 + g8;
      xsf[wb +  0] = float4{q0.x, q0.y, q0.z, 0.f};
      xsf[wb +  8] = float4{q0.w, q1.x, q1.y, 0.f};
      xsf[wb + 16] = float4{q1.z, q1.w, q2.x, 0.f};
      xsf[wb + 24] = float4{q2.y, q2.z, q2.w, 0.f};
    }
    if (ch < 2) {
      const float* xc = xc0 + (ch + 2) * 384;
      q0 = *(const float4*)(xc + 0);
      q1 = *(const float4*)(xc + 4);
      q2 = *(const float4*)(xc + 8);
    }

    // second half of the chunk
#pragma unroll 2
    for (int v = 64; v < 128; ++v) step(base + v, v & 1);
  }

  // final timestep's output (uses h_{S-1})
  {
    float hbr[16];
    const int hvi = __float_as_int(h);
    BCAST_ALL();
    float oa0 = bl, oa1 = 0.f;
#pragma unroll
    for (int e = 0; e < 8; e += 2) {
      oa0 = fmaf(hbr[hh * 8 + e],     wl[e],     oa0);
      oa1 = fmaf(hbr[hh * 8 + e + 1], wl[e + 1], oa1);
    }
    const float oal = oa0 + oa1;
    const float oa = oal + swz16(oal);
    if (storer) {
      ob[(TS - 1) * 5] = fminf(fmaxf(oa, -10.0f), 10.0f);
    }
  }
}

extern "C" void kernel_launch(void* const* d_in, const int* in_sizes, int n_in,
                              void* d_out, int out_size, void* d_ws, size_t ws_size,
                              hipStream_t stream) {
  const float* x     = (const float*)d_in[0];
  const float* W_ih  = (const float*)d_in[1];
  const float* W_hh  = (const float*)d_in[2];
  const float* b_ih  = (const float*)d_in[3];
  const float* b_hh  = (const float*)d_in[4];
  const float* W_lin = (const float*)d_in[5];
  const float* b_lin = (const float*)d_in[6];
  float* out = (float*)d_out;

  const int B = in_sizes[0] / (TS * 3);   // 4096
  const int grid = B / 8;                 // 8 batches per 256-thread block
  lstm_enc_kernel<<<grid, 256, 0, stream>>>(x, W_ih, W_hh, b_ih, b_hh, W_lin, b_lin, out);
}

// Round 7
// 258.106 us; speedup vs baseline: 3.2540x; 3.2540x over previous
//
#include <hip/hip_runtime.h>

// SimpleEncoder R12: LSTM(B=4096,S=512,I=3,H=16) + Linear(16->5) + clip(+-10)
//
// R10/R11's 797us was NOT the algorithm and NOT waves_per_eu: it was
// rule-#20 scratch demotion. The head loop indexed hbr[hh*8+e] with
// RUNTIME hh -> the whole hbr[16] array went to scratch -> 16 scratch
// writes + reloads per step (VALUBusy 19%, +9MB WRITE_SIZE, dur
// attribute-insensitive: R10==R11==797us at VGPR 64 vs 88). R8 never had
// this bug (static hbr[e]) -> its 208us was a clean 2-wave build.
//
// R12 = R10 with the head made fully static: every lane loads the FULL
// wl[16] and computes the complete head dot (16 fma, static hbr[k]);
// replaces 8 fma + swz16-reduce + runtime-indexed gather. Same op count,
// one fewer swizzle, no cross-half dep on the store path, and hbr[16]
// stays in registers.
//
// Structure (unchanged): GATE-split, 32 lanes/batch, 2 waves/SIMD.
// lane (u = l&15, hh = (l>>4)&1) computes gates (i,f) [hh=0] or (g,o)
// [hh=1] for unit u -- 2 full-length dots/lane.
//  - MAC issue conserved per batch (19 pk_fma/lane).
//  - gate trans conserved: halves compute DIFFERENT gates in the SAME
//    instructions; signs folded into per-lane weight scales {L,L,-2L,L};
//    all lanes run E=exp2(-z), paired rcp.
//  - gate exchange: 2 ds_swizzle xor-16; cell update redundant in both
//    halves (bit-identical copies -> h coherent).
//  - per-wave-only duplication: 16-DPP bcast + cell trans + loop.
// Keeps R9's scaled-cs recurrence + quad accumulation chains.
// Grid: 8 batches/block, 512 blocks x 256 thr; waves_per_eu(2,2).

#define TS 512
#define LOG2E 1.44269504088896340736f

typedef float f32x2 __attribute__((ext_vector_type(2)));

// DPP row_newbcast:K -- broadcast lane K of each 16-lane row to the row.
#define BCAST(K) hbr[K] = __int_as_float( \
    __builtin_amdgcn_update_dpp(0, hvi, 0x150 + (K), 0xf, 0xf, true))
#define BCAST_ALL() \
  BCAST(0); BCAST(1); BCAST(2); BCAST(3); BCAST(4); BCAST(5); BCAST(6); BCAST(7); \
  BCAST(8); BCAST(9); BCAST(10); BCAST(11); BCAST(12); BCAST(13); BCAST(14); BCAST(15)

// xor-16 lane swap within each 32-lane group (ds_swizzle BitMode 0x401F)
static __device__ __forceinline__ float swz16(float v) {
  return __int_as_float(__builtin_amdgcn_ds_swizzle(__float_as_int(v), 0x401F));
}

__global__ __launch_bounds__(256)
__attribute__((amdgpu_waves_per_eu(2, 2)))
void lstm_enc_kernel(const float* __restrict__ x,
                     const float* __restrict__ W_ih,
                     const float* __restrict__ W_hh,
                     const float* __restrict__ b_ih,
                     const float* __restrict__ b_hh,
                     const float* __restrict__ W_lin,
                     const float* __restrict__ b_lin,
                     float* __restrict__ out) {
  const int tid = threadIdx.x;
  const int u   = tid & 15;          // hidden unit
  const int hh  = (tid >> 4) & 1;    // gate-half: 0 -> (i,f), 1 -> (g,o)
  const int g8  = tid >> 5;          // batch slot within block (0..7)
  const int batch = blockIdx.x * 8 + g8;
  const int jo = (u < 5) ? u : 0;    // clamped row for W_lin loads

  // x staging: xs[parity][step-in-chunk(128)][batch-slot] as float4 (pad 4th)
  __shared__ float4 xs[2][128][8];
  float4* xsf = &xs[0][0][0];        // flat: idx = (s & 255)*8 + g8

  // ---- per-lane weights: this lane's GATE PAIR, full k, signs+log2e folded.
  // hh=0: rows (u, u+16) scales (L, L)      -> z = (L i, L f),  E=exp2(-z)
  // hh=1: rows (u+32, u+48) scales (-2L, L) -> z = (-2L g, L o), E=exp2(-z)
  //   sg = rcp(1+exp2(2L g)) = 1/(1+e^{2g}); og = sigmoid(o)  [paired rcp]
  const int r0 = u + (hh ? 32 : 0);
  const int r1 = u + (hh ? 48 : 16);
  const float s0 = hh ? (-2.0f * LOG2E) : LOG2E;
  const float s1 = LOG2E;

  f32x2 wp[16];                      // {W[r0][k]*s0, W[r1][k]*s1}
  float wl[16];                      // FULL head row (static indexing!)
#pragma unroll
  for (int k = 0; k < 16; ++k) {
    wp[k] = f32x2{W_hh[r0 * 16 + k] * s0, W_hh[r1 * 16 + k] * s1};
    wl[k] = W_lin[jo * 16 + k];
  }
  f32x2 xwp[3];
#pragma unroll
  for (int i = 0; i < 3; ++i) {
    xwp[i] = f32x2{W_ih[r0 * 3 + i] * s0, W_ih[r1 * 3 + i] * s1};
  }
  const f32x2 bp = f32x2{(b_ih[r0] + b_hh[r0]) * s0,
                         (b_ih[r1] + b_hh[r1]) * s1};
  const float bl = b_lin[jo];

  const float* __restrict__ xb = x + (size_t)batch * (TS * 3);
  float* __restrict__ ob = out + (size_t)batch * (TS * 5) + u;
  const bool storer = (u < 5) && (hh == 0);

  // ---- staging: 128-step chunks (384 floats/batch); lane l32 = tid&31 owns
  // steps 4*l32..4*l32+3 of batch slot g8. Intra-wave -> no barriers.
  const int l32 = tid & 31;
  const float* xc0 = xb + l32 * 12;
  float4 q0, q1, q2;
  q0 = *(const float4*)(xc0 + 0);
  q1 = *(const float4*)(xc0 + 4);
  q2 = *(const float4*)(xc0 + 8);
  {
    const int wb = (l32 * 4) * 8 + g8;     // parity 0 base
    xsf[wb +  0] = float4{q0.x, q0.y, q0.z, 0.f};
    xsf[wb +  8] = float4{q0.w, q1.x, q1.y, 0.f};
    xsf[wb + 16] = float4{q1.z, q1.w, q2.x, 0.f};
    xsf[wb + 24] = float4{q2.y, q2.z, q2.w, 0.f};
  }
  q0 = *(const float4*)(xc0 + 384 + 0);
  q1 = *(const float4*)(xc0 + 384 + 4);
  q2 = *(const float4*)(xc0 + 384 + 8);

  // prefetch x for steps 0 and 1
  float4 xr[2];
  xr[0] = xsf[0 * 8 + g8];
  xr[1] = xsf[1 * 8 + g8];

  float h = 0.0f, cs = 0.0f;         // cs = 2*LOG2E * c (scaled cell)

  auto step = [&](int s, int slot) {
    const float4 xt = xr[slot];
    // issue ds_read for step s+2 into the slot just freed
    xr[slot] = xsf[(((s + 2) & 255) << 3) + g8];

    // broadcast h_{t-1} across each 16-lane row (hbr[k] = h[k] of OUR batch)
    float hbr[16];
    const int hvi = __float_as_int(h);
    BCAST_ALL();

    // this lane's gate-pair pre-activations: quad pk_fma chains (depth ~5)
    f32x2 aa = bp, ab = f32x2{0.f, 0.f}, ac = f32x2{0.f, 0.f}, ad = f32x2{0.f, 0.f};
    float oa0 = bl, oa1 = 0.f;
    aa = f32x2{xt.x, xt.x} * xwp[0] + aa;
    ab = f32x2{xt.y, xt.y} * xwp[1] + ab;
    ac = f32x2{xt.z, xt.z} * xwp[2] + ac;
#pragma unroll
    for (int k = 0; k < 16; k += 4) {
      const f32x2 h0 = f32x2{hbr[k],     hbr[k]};
      const f32x2 h1 = f32x2{hbr[k + 1], hbr[k + 1]};
      const f32x2 h2 = f32x2{hbr[k + 2], hbr[k + 2]};
      const f32x2 h3 = f32x2{hbr[k + 3], hbr[k + 3]};
      aa = h0 * wp[k]     + aa;
      ab = h1 * wp[k + 1] + ab;
      ac = h2 * wp[k + 2] + ac;
      ad = h3 * wp[k + 3] + ad;
      // full head dot, STATIC indices (every lane; only storers use it)
      oa0 = fmaf(hbr[k],     wl[k],     oa0);
      oa1 = fmaf(hbr[k + 1], wl[k + 1], oa1);
      oa0 = fmaf(hbr[k + 2], wl[k + 2], oa0);
      oa1 = fmaf(hbr[k + 3], wl[k + 3], oa1);
    }
    const f32x2 z = (aa + ab) + (ac + ad);

    // head store out[s-1] (no cross-lane reduce needed: full dot per lane)
    if (s > 0 && storer) {
      const float oa = oa0 + oa1;
      ob[(s - 1) * 5] = fminf(fmaxf(oa, -10.0f), 10.0f);
    }

    // uniform paired-rcp acts: hh=0 -> (v0,v1)=(ig,fg); hh=1 -> (sg,og)
    const float E0 = __builtin_amdgcn_exp2f(-z.x);
    const float E1 = __builtin_amdgcn_exp2f(-z.y);
    const float d0 = 1.0f + E0, d1 = 1.0f + E1;
    const float R  = __builtin_amdgcn_rcpf(d0 * d1);
    const float v0 = d1 * R;
    const float v1 = d0 * R;

    // exchange with the other half (bitwise copies -> both halves coherent)
    const float w0 = swz16(v0);
    const float w1 = swz16(v1);
    const float ig = hh ? w0 : v0;
    const float fg = hh ? w1 : v1;
    const float sg = hh ? v0 : w0;
    const float og = hh ? v1 : w1;

    // scaled cell: cs = 2L*c; gg2 = 2L*tanh(g) = 2L - 4L*sg
    const float gg2 = fmaf(-4.0f * LOG2E, sg, 2.0f * LOG2E);
    cs = fmaf(fg, cs, ig * gg2);
    const float tc = fmaf(-2.0f,
        __builtin_amdgcn_rcpf(1.0f + __builtin_amdgcn_exp2f(cs)), 1.0f);
    h = og * tc;
  };

  for (int ch = 0; ch < 4; ++ch) {
    const int base = ch * 128;

    // first half of the chunk
#pragma unroll 2
    for (int v = 0; v < 64; ++v) step(base + v, v & 1);

    // mid-chunk: stage chunk ch+1 (regs loaded ~128 steps ago), start ch+2 loads
    if (ch < 3) {
      const int p = (ch + 1) & 1;
      const int wb = (p * 128 + l32 * 4) * 8 + g8;
      xsf[wb +  0] = float4{q0.x, q0.y, q0.z, 0.f};
      xsf[wb +  8] = float4{q0.w, q1.x, q1.y, 0.f};
      xsf[wb + 16] = float4{q1.z, q1.w, q2.x, 0.f};
      xsf[wb + 24] = float4{q2.y, q2.z, q2.w, 0.f};
    }
    if (ch < 2) {
      const float* xc = xc0 + (ch + 2) * 384;
      q0 = *(const float4*)(xc + 0);
      q1 = *(const float4*)(xc + 4);
      q2 = *(const float4*)(xc + 8);
    }

    // second half of the chunk
#pragma unroll 2
    for (int v = 64; v < 128; ++v) step(base + v, v & 1);
  }

  // final timestep's output (uses h_{S-1}; full static head dot)
  {
    float hbr[16];
    const int hvi = __float_as_int(h);
    BCAST_ALL();
    float oa0 = bl, oa1 = 0.f;
#pragma unroll
    for (int k = 0; k < 16; k += 2) {
      oa0 = fmaf(hbr[k],     wl[k],     oa0);
      oa1 = fmaf(hbr[k + 1], wl[k + 1], oa1);
    }
    if (storer) {
      const float oa = oa0 + oa1;
      ob[(TS - 1) * 5] = fminf(fmaxf(oa, -10.0f), 10.0f);
    }
  }
}

extern "C" void kernel_launch(void* const* d_in, const int* in_sizes, int n_in,
                              void* d_out, int out_size, void* d_ws, size_t ws_size,
                              hipStream_t stream) {
  const float* x     = (const float*)d_in[0];
  const float* W_ih  = (const float*)d_in[1];
  const float* W_hh  = (const float*)d_in[2];
  const float* b_ih  = (const float*)d_in[3];
  const float* b_hh  = (const float*)d_in[4];
  const float* W_lin = (const float*)d_in[5];
  const float* b_lin = (const float*)d_in[6];
  float* out = (float*)d_out;

  const int B = in_sizes[0] / (TS * 3);   // 4096
  const int grid = B / 8;                 // 8 batches per 256-thread block
  lstm_enc_kernel<<<grid, 256, 0, stream>>>(x, W_ih, W_hh, b_ih, b_hh, W_lin, b_lin, out);
}

// Round 8
// 254.579 us; speedup vs baseline: 3.2991x; 1.0139x over previous
//
#include <hip/hip_runtime.h>

// SimpleEncoder R13: LSTM(B=4096,S=512,I=3,H=16) + Linear(16->5) + clip(+-10)
//
// R13 = R12 + WAVE DE-PHASING. One change.
//
// R12 (202us) fixed the scratch bug (WRITE_SIZE back to 40960) but realized
// ZERO overlap from 2 waves/SIMD: wall 947 = 652 busy + 295 idle, and the
// idle equals R5's 1-wave idle (287). Diagnosis: the two co-resident waves
// run identical instruction streams, start together, issue at the same
// rate -> they stay PHASE-LOCKED and hit their acts-chain stalls at the
// same cycles. The SIMD idles as if single-wave, while we pay the
// gate-split's duplicated acts/scaffold (+232 busy vs R5).
//
// Fix: delay each wave's loop entry by slot*~190cyc where slot = the HW
// wave-slot ID (s_getreg HW_ID[3:0]). Co-resident waves on a SIMD occupy
// DIFFERENT slots by construction -> guaranteed distinct offsets. No
// barriers in the loop + equal issue rates -> offset persists across all
// 512 steps; wave A's chain stall overlaps wave B's MAC burst.
// Steady-state wall -> max(2*I, C); I~326 -> predicted ~660 cyc/step
// (~140us) if issue-bound; the measured wall also tells us C directly.
//
// Structure (unchanged from R12): GATE-split, 32 lanes/batch, 2 waves/SIMD,
// static full head dot, paired-rcp acts, 2 ds_swizzle gate exchange,
// scaled-cs recurrence, quad MAC chains, intra-wave LDS x staging.
// Grid: 8 batches/block, 512 blocks x 256 thr; waves_per_eu(2,2).

#define TS 512
#define LOG2E 1.44269504088896340736f

typedef float f32x2 __attribute__((ext_vector_type(2)));

// DPP row_newbcast:K -- broadcast lane K of each 16-lane row to the row.
#define BCAST(K) hbr[K] = __int_as_float( \
    __builtin_amdgcn_update_dpp(0, hvi, 0x150 + (K), 0xf, 0xf, true))
#define BCAST_ALL() \
  BCAST(0); BCAST(1); BCAST(2); BCAST(3); BCAST(4); BCAST(5); BCAST(6); BCAST(7); \
  BCAST(8); BCAST(9); BCAST(10); BCAST(11); BCAST(12); BCAST(13); BCAST(14); BCAST(15)

// xor-16 lane swap within each 32-lane group (ds_swizzle BitMode 0x401F)
static __device__ __forceinline__ float swz16(float v) {
  return __int_as_float(__builtin_amdgcn_ds_swizzle(__float_as_int(v), 0x401F));
}

__global__ __launch_bounds__(256)
__attribute__((amdgpu_waves_per_eu(2, 2)))
void lstm_enc_kernel(const float* __restrict__ x,
                     const float* __restrict__ W_ih,
                     const float* __restrict__ W_hh,
                     const float* __restrict__ b_ih,
                     const float* __restrict__ b_hh,
                     const float* __restrict__ W_lin,
                     const float* __restrict__ b_lin,
                     float* __restrict__ out) {
  const int tid = threadIdx.x;
  const int u   = tid & 15;          // hidden unit
  const int hh  = (tid >> 4) & 1;    // gate-half: 0 -> (i,f), 1 -> (g,o)
  const int g8  = tid >> 5;          // batch slot within block (0..7)
  const int batch = blockIdx.x * 8 + g8;
  const int jo = (u < 5) ? u : 0;    // clamped row for W_lin loads

  // x staging: xs[parity][step-in-chunk(128)][batch-slot] as float4 (pad 4th)
  __shared__ float4 xs[2][128][8];
  float4* xsf = &xs[0][0][0];        // flat: idx = (s & 255)*8 + g8

  // ---- per-lane weights: this lane's GATE PAIR, full k, signs+log2e folded.
  // hh=0: rows (u, u+16) scales (L, L)      -> z = (L i, L f),  E=exp2(-z)
  // hh=1: rows (u+32, u+48) scales (-2L, L) -> z = (-2L g, L o), E=exp2(-z)
  //   sg = rcp(1+exp2(2L g)) = 1/(1+e^{2g}); og = sigmoid(o)  [paired rcp]
  const int r0 = u + (hh ? 32 : 0);
  const int r1 = u + (hh ? 48 : 16);
  const float s0 = hh ? (-2.0f * LOG2E) : LOG2E;
  const float s1 = LOG2E;

  f32x2 wp[16];                      // {W[r0][k]*s0, W[r1][k]*s1}
  float wl[16];                      // FULL head row (static indexing)
#pragma unroll
  for (int k = 0; k < 16; ++k) {
    wp[k] = f32x2{W_hh[r0 * 16 + k] * s0, W_hh[r1 * 16 + k] * s1};
    wl[k] = W_lin[jo * 16 + k];
  }
  f32x2 xwp[3];
#pragma unroll
  for (int i = 0; i < 3; ++i) {
    xwp[i] = f32x2{W_ih[r0 * 3 + i] * s0, W_ih[r1 * 3 + i] * s1};
  }
  const f32x2 bp = f32x2{(b_ih[r0] + b_hh[r0]) * s0,
                         (b_ih[r1] + b_hh[r1]) * s1};
  const float bl = b_lin[jo];

  const float* __restrict__ xb = x + (size_t)batch * (TS * 3);
  float* __restrict__ ob = out + (size_t)batch * (TS * 5) + u;
  const bool storer = (u < 5) && (hh == 0);

  // ---- staging: 128-step chunks (384 floats/batch); lane l32 = tid&31 owns
  // steps 4*l32..4*l32+3 of batch slot g8. Intra-wave -> no barriers.
  const int l32 = tid & 31;
  const float* xc0 = xb + l32 * 12;
  float4 q0, q1, q2;
  q0 = *(const float4*)(xc0 + 0);
  q1 = *(const float4*)(xc0 + 4);
  q2 = *(const float4*)(xc0 + 8);
  {
    const int wb = (l32 * 4) * 8 + g8;     // parity 0 base
    xsf[wb +  0] = float4{q0.x, q0.y, q0.z, 0.f};
    xsf[wb +  8] = float4{q0.w, q1.x, q1.y, 0.f};
    xsf[wb + 16] = float4{q1.z, q1.w, q2.x, 0.f};
    xsf[wb + 24] = float4{q2.y, q2.z, q2.w, 0.f};
  }
  q0 = *(const float4*)(xc0 + 384 + 0);
  q1 = *(const float4*)(xc0 + 384 + 4);
  q2 = *(const float4*)(xc0 + 384 + 8);

  // prefetch x for steps 0 and 1
  float4 xr[2];
  xr[0] = xsf[0 * 8 + g8];
  xr[1] = xsf[1 * 8 + g8];

  // ---- DE-PHASE: distinct start delay per HW wave slot. Co-resident waves
  // on a SIMD have different slot IDs -> guaranteed distinct offsets
  // (~192 cyc/slot ~ half a step's issue). Wave-uniform; no correctness
  // impact (no inter-wave deps anywhere in the main loop).
  {
    // hwreg(HW_REG_HW_ID=4, offset=0, size=4) -> imm = 4 | (0<<6) | (3<<11)
    const unsigned slot = __builtin_amdgcn_s_getreg(4 | (3 << 11)) & 0xF;
    for (unsigned i = 0; i < slot; ++i) __builtin_amdgcn_s_sleep(3);
  }

  float h = 0.0f, cs = 0.0f;         // cs = 2*LOG2E * c (scaled cell)

  auto step = [&](int s, int slot) {
    const float4 xt = xr[slot];
    // issue ds_read for step s+2 into the slot just freed
    xr[slot] = xsf[(((s + 2) & 255) << 3) + g8];

    // broadcast h_{t-1} across each 16-lane row (hbr[k] = h[k] of OUR batch)
    float hbr[16];
    const int hvi = __float_as_int(h);
    BCAST_ALL();

    // this lane's gate-pair pre-activations: quad pk_fma chains (depth ~5)
    f32x2 aa = bp, ab = f32x2{0.f, 0.f}, ac = f32x2{0.f, 0.f}, ad = f32x2{0.f, 0.f};
    float oa0 = bl, oa1 = 0.f;
    aa = f32x2{xt.x, xt.x} * xwp[0] + aa;
    ab = f32x2{xt.y, xt.y} * xwp[1] + ab;
    ac = f32x2{xt.z, xt.z} * xwp[2] + ac;
#pragma unroll
    for (int k = 0; k < 16; k += 4) {
      const f32x2 h0 = f32x2{hbr[k],     hbr[k]};
      const f32x2 h1 = f32x2{hbr[k + 1], hbr[k + 1]};
      const f32x2 h2 = f32x2{hbr[k + 2], hbr[k + 2]};
      const f32x2 h3 = f32x2{hbr[k + 3], hbr[k + 3]};
      aa = h0 * wp[k]     + aa;
      ab = h1 * wp[k + 1] + ab;
      ac = h2 * wp[k + 2] + ac;
      ad = h3 * wp[k + 3] + ad;
      // full head dot, STATIC indices (every lane; only storers use it)
      oa0 = fmaf(hbr[k],     wl[k],     oa0);
      oa1 = fmaf(hbr[k + 1], wl[k + 1], oa1);
      oa0 = fmaf(hbr[k + 2], wl[k + 2], oa0);
      oa1 = fmaf(hbr[k + 3], wl[k + 3], oa1);
    }
    const f32x2 z = (aa + ab) + (ac + ad);

    // head store out[s-1] (no cross-lane reduce needed: full dot per lane)
    if (s > 0 && storer) {
      const float oa = oa0 + oa1;
      ob[(s - 1) * 5] = fminf(fmaxf(oa, -10.0f), 10.0f);
    }

    // uniform paired-rcp acts: hh=0 -> (v0,v1)=(ig,fg); hh=1 -> (sg,og)
    const float E0 = __builtin_amdgcn_exp2f(-z.x);
    const float E1 = __builtin_amdgcn_exp2f(-z.y);
    const float d0 = 1.0f + E0, d1 = 1.0f + E1;
    const float R  = __builtin_amdgcn_rcpf(d0 * d1);
    const float v0 = d1 * R;
    const float v1 = d0 * R;

    // exchange with the other half (bitwise copies -> both halves coherent)
    const float w0 = swz16(v0);
    const float w1 = swz16(v1);
    const float ig = hh ? w0 : v0;
    const float fg = hh ? w1 : v1;
    const float sg = hh ? v0 : w0;
    const float og = hh ? v1 : w1;

    // scaled cell: cs = 2L*c; gg2 = 2L*tanh(g) = 2L - 4L*sg
    const float gg2 = fmaf(-4.0f * LOG2E, sg, 2.0f * LOG2E);
    cs = fmaf(fg, cs, ig * gg2);
    const float tc = fmaf(-2.0f,
        __builtin_amdgcn_rcpf(1.0f + __builtin_amdgcn_exp2f(cs)), 1.0f);
    h = og * tc;
  };

  for (int ch = 0; ch < 4; ++ch) {
    const int base = ch * 128;

    // first half of the chunk
#pragma unroll 2
    for (int v = 0; v < 64; ++v) step(base + v, v & 1);

    // mid-chunk: stage chunk ch+1 (regs loaded ~128 steps ago), start ch+2 loads
    if (ch < 3) {
      const int p = (ch + 1) & 1;
      const int wb = (p * 128 + l32 * 4) * 8 + g8;
      xsf[wb +  0] = float4{q0.x, q0.y, q0.z, 0.f};
      xsf[wb +  8] = float4{q0.w, q1.x, q1.y, 0.f};
      xsf[wb + 16] = float4{q1.z, q1.w, q2.x, 0.f};
      xsf[wb + 24] = float4{q2.y, q2.z, q2.w, 0.f};
    }
    if (ch < 2) {
      const float* xc = xc0 + (ch + 2) * 384;
      q0 = *(const float4*)(xc + 0);
      q1 = *(const float4*)(xc + 4);
      q2 = *(const float4*)(xc + 8);
    }

    // second half of the chunk
#pragma unroll 2
    for (int v = 64; v < 128; ++v) step(base + v, v & 1);
  }

  // final timestep's output (uses h_{S-1}; full static head dot)
  {
    float hbr[16];
    const int hvi = __float_as_int(h);
    BCAST_ALL();
    float oa0 = bl, oa1 = 0.f;
#pragma unroll
    for (int k = 0; k < 16; k += 2) {
      oa0 = fmaf(hbr[k],     wl[k],     oa0);
      oa1 = fmaf(hbr[k + 1], wl[k + 1], oa1);
    }
    if (storer) {
      const float oa = oa0 + oa1;
      ob[(TS - 1) * 5] = fminf(fmaxf(oa, -10.0f), 10.0f);
    }
  }
}

extern "C" void kernel_launch(void* const* d_in, const int* in_sizes, int n_in,
                              void* d_out, int out_size, void* d_ws, size_t ws_size,
                              hipStream_t stream) {
  const float* x     = (const float*)d_in[0];
  const float* W_ih  = (const float*)d_in[1];
  const float* W_hh  = (const float*)d_in[2];
  const float* b_ih  = (const float*)d_in[3];
  const float* b_hh  = (const float*)d_in[4];
  const float* W_lin = (const float*)d_in[5];
  const float* b_lin = (const float*)d_in[6];
  float* out = (float*)d_out;

  const int B = in_sizes[0] / (TS * 3);   // 4096
  const int grid = B / 8;                 // 8 batches per 256-thread block
  lstm_enc_kernel<<<grid, 256, 0, stream>>>(x, W_ih, W_hh, b_ih, b_hh, W_lin, b_lin, out);
}